// Round 7
// baseline (1475.174 us; speedup 1.0000x reference)
//
#include <hip/hip_runtime.h>

#define B_ 1024
#define S_ 64
#define D_ 300
#define DP_ 320
#define H_ 512
#define G3_ 1536
#define Z_ 128
#define NC1 10
#define NC2 16
#define CSTR 64   // counter stride in dwords (256 B) — one L3 line per group

typedef __bf16 bf16x8 __attribute__((ext_vector_type(8)));
typedef float f32x4 __attribute__((ext_vector_type(4)));

// cached global->LDS DMA (aux=0)
#define GLLD(g, l) __builtin_amdgcn_global_load_lds( \
    (const __attribute__((address_space(1))) void*)(g), \
    (__attribute__((address_space(3))) void*)(l), 16, 0, 0)
// coherence-point global->LDS DMA: aux=17 = SC0|SC1 -> bypass L1+L2
#define GLLD_CP(g, l) __builtin_amdgcn_global_load_lds( \
    (const __attribute__((address_space(1))) void*)(g), \
    (__attribute__((address_space(3))) void*)(l), 16, 0, 17)

#define MFMA(a, b, c) __builtin_amdgcn_mfma_f32_16x16x32_bf16((a), (b), (c), 0, 0, 0)

// ---------------- prep kernels ----------------
__global__ __launch_bounds__(256) void prep_cnt(unsigned* __restrict__ cnt) {
    int i = blockIdx.x * 256 + threadIdx.x;        // 2048 = 32 groups * 64 stride
    __hip_atomic_store(cnt + i, 0u, __ATOMIC_RELAXED, __HIP_MEMORY_SCOPE_AGENT);
}

// text is [b][s][d]; Xbf re-laid-out to [s][b][dp] so each step's tile is contiguous
__global__ __launch_bounds__(320) void prep_text(const float* __restrict__ text,
                                                 __bf16* __restrict__ Xbf) {
    int bs = blockIdx.x;          // 65536 = B*S, bs = b*S + s
    int b = bs >> 6, s = bs & 63;
    int dp = threadIdx.x;         // 320
    float v = (dp < D_) ? text[(size_t)bs * D_ + dp] : 0.f;
    Xbf[((size_t)s * B_ + b) * DP_ + dp] = (__bf16)v;
}

__global__ __launch_bounds__(256) void prep_w(
    const float* __restrict__ Wih_f, const float* __restrict__ Whh_f,
    const float* __restrict__ Wih_b, const float* __restrict__ Whh_b,
    const float* __restrict__ W_mu, const float* __restrict__ W_sig,
    __bf16* __restrict__ Wk1, __bf16* __restrict__ Wk2, __bf16* __restrict__ Wcat) {
    const int n1 = 2 * G3_ * DP_;       // 983040
    const int n2 = 2 * G3_ * H_;        // 1572864
    int i = blockIdx.x * 256 + threadIdx.x;
    if (i < n1) {
        int dir = i / (G3_ * DP_);
        int rem = i - dir * (G3_ * DP_);
        int r = rem / DP_;
        int k = rem - r * DP_;
        const float* W = dir ? Wih_b : Wih_f;
        Wk1[i] = (k < D_) ? (__bf16)W[(size_t)r * D_ + k] : (__bf16)0.f;
    } else if (i < n1 + n2) {
        int jj = i - n1;
        int dir = jj / (G3_ * H_);
        int rem = jj - dir * (G3_ * H_);
        int r = rem / H_;
        int k = rem - r * H_;
        const float* W = dir ? Whh_b : Whh_f;
        Wk2[jj] = (__bf16)W[(size_t)r * H_ + k];
    } else {
        int idx = i - n1 - n2;          // < 131072
        int z = idx >> 9, k = idx & 511;
        Wcat[idx] = (__bf16)(z < 128 ? W_mu[(size_t)z * H_ + k]
                                     : W_sig[(size_t)(z - 128) * H_ + k]);
    }
}

// ---------------- persistent bidirectional GRU ----------------
// 256 blocks, 256 threads (4 waves). Block = 64 batch rows x 64 h-cols of one
// direction. Weights register/AGPR-resident across all 64 steps. h and the
// masked sum register-resident. Cross-block h exchange: writers publish bf16 h
// with agent-scope relaxed atomic stores (write-through to L3); readers pull h
// with global_load_lds aux=SC0|SC1 (L3-coherent reads, L1/L2 stay hot for X).
// Step barrier = per-row-group atomic counters, ONE PER 256-B LINE (CSTR) so
// the 32 groups' barrier traffic doesn't serialize on a single hot L3 line.
// s=0 skips the exchange (h0 = 0, bhh folded into biases).
__global__ __launch_bounds__(256, 1) void gru_persist(
    const __bf16* __restrict__ Xbf, const __bf16* __restrict__ Wk1,
    const __bf16* __restrict__ Wk2,
    const float* __restrict__ bih_f, const float* __restrict__ bhh_f,
    const float* __restrict__ bih_b, const float* __restrict__ bhh_b,
    const int* __restrict__ lens,
    __bf16* __restrict__ Hb0, __bf16* __restrict__ Hb1,
    float* __restrict__ Ssum, unsigned* __restrict__ cnt)
{
    __shared__ __align__(16) __bf16 hbuf[NC2 * 2048];   // 64 KB static

    const int bid = blockIdx.x;
    const int xcd = bid & 7, slot = bid >> 3;
    const int dir = xcd >> 2;                      // perf heuristic only
    const int mb  = (xcd & 3) * 4 + (slot >> 3);   // 0..15
    const int jb  = slot & 7;                      // 0..7
    const int b0  = mb * 64;
    const int group = dir * 16 + mb;
    unsigned* const gcnt = cnt + group * CSTR;     // private 256-B line per group

    const int tid = threadIdx.x;
    const int wave = tid >> 6;
    const int lane = tid & 63;

    const int jcol = jb * 64 + wave * 16 + (lane & 15);    // 0..511
    const int kq8  = (lane >> 4) * 8;

    __bf16* HB[2] = { Hb0, Hb1 };
    // h staging geometry (thread -> row, col-quad), matches chunk layout [64][32]
    const int srow = tid >> 2;
    const int scol = (tid & 3) * 8;
    const size_t hrow = (size_t)(dir * B_ + b0 + srow) * H_ + scol;

    // per-lane X base: row b0+(lane&15), col kq8 (chunk c adds c*32, mt adds 16*DP_)
    const __bf16* xlane = Xbf + (size_t)(b0 + (lane & 15)) * DP_ + kq8;

    // ---- one-time: load BOTH weight slices into registers ----
    bf16x8 w1c[NC1][3];   // Wih fragments
    bf16x8 w2c[NC2][3];   // Whh fragments
    {
        const __bf16* w1p[3];
        const __bf16* w2p[3];
#pragma unroll
        for (int g = 0; g < 3; ++g) {
            w1p[g] = Wk1 + ((size_t)dir * G3_ + g * H_ + jcol) * DP_ + kq8;
            w2p[g] = Wk2 + ((size_t)dir * G3_ + g * H_ + jcol) * H_ + kq8;
        }
#pragma unroll
        for (int c = 0; c < NC1; ++c)
#pragma unroll
            for (int g = 0; g < 3; ++g)
                w1c[c][g] = *(const bf16x8*)(w1p[g] + c * 32);
#pragma unroll
        for (int c = 0; c < NC2; ++c)
#pragma unroll
            for (int g = 0; g < 3; ++g)
                w2c[c][g] = *(const bf16x8*)(w2p[g] + c * 32);
    }

    const float* bih = dir ? bih_b : bih_f;
    const float* bhh = dir ? bhh_b : bhh_f;
    const float b_r  = bih[jcol] + bhh[jcol];
    const float b_z  = bih[H_ + jcol] + bhh[H_ + jcol];
    const float b_ni = bih[2 * H_ + jcol];
    const float b_nh = bhh[2 * H_ + jcol];

    unsigned lenp[4];
#pragma unroll
    for (int mt = 0; mt < 4; ++mt) {
        int r0 = b0 + mt * 16 + (lane >> 4) * 4;
        lenp[mt] = (unsigned)(lens[r0] & 255) | ((unsigned)(lens[r0 + 1] & 255) << 8)
                 | ((unsigned)(lens[r0 + 2] & 255) << 16) | ((unsigned)(lens[r0 + 3] & 255) << 24);
    }

    float hreg[16], ssum[16];
#pragma unroll
    for (int i = 0; i < 16; ++i) { hreg[i] = 0.f; ssum[i] = 0.f; }

    const int aoff = (lane & 15) * 32 + kq8;

    for (int s = 0; s < S_; ++s) {
        const int sx = dir ? (S_ - 1 - s) : s;
        const __bf16* xs = xlane + (size_t)sx * (B_ * DP_);

        f32x4 acc[4][4];
#pragma unroll
        for (int mt = 0; mt < 4; ++mt)
#pragma unroll
            for (int p = 0; p < 4; ++p)
                acc[mt][p] = (f32x4){0.f, 0.f, 0.f, 0.f};

        // ---- phase 1: x @ Wih^T (W in registers, X from L2; overlaps peers' tail) ----
#pragma unroll
        for (int c = 0; c < NC1; ++c) {
            bf16x8 af[4];
#pragma unroll
            for (int mt = 0; mt < 4; ++mt)
                af[mt] = *(const bf16x8*)(xs + mt * (16 * DP_) + c * 32);
#pragma unroll
            for (int mt = 0; mt < 4; ++mt) {
                acc[mt][0] = MFMA(af[mt], w1c[c][0], acc[mt][0]);
                acc[mt][1] = MFMA(af[mt], w1c[c][1], acc[mt][1]);
                acc[mt][2] = MFMA(af[mt], w1c[c][2], acc[mt][2]);
            }
        }

        if (s > 0) {
            // ---- wait for group peers to finish step s-1 (private line per group) ----
            if (tid == 0) {
                const unsigned tgt = 8u * (unsigned)s;
                while (__hip_atomic_load(gcnt, __ATOMIC_RELAXED,
                                         __HIP_MEMORY_SCOPE_AGENT) < tgt) {}
            }
            __syncthreads();

            // ---- stage h via pipelined L3-coherent global->LDS DMA ----
            {
                const __bf16* src = HB[s & 1] + hrow;     // per-lane source
                __bf16* dst = hbuf + wave * 512;          // wave-uniform + lane*16B
#pragma unroll
                for (int c = 0; c < NC2; ++c)
                    GLLD_CP(src + c * 32, dst + c * 2048);
            }
            __syncthreads();   // vmcnt(0) drains the DMA

            // ---- phase 2: h @ Whh^T (W in registers) ----
#pragma unroll
            for (int c = 0; c < NC2; ++c) {
                bf16x8 af[4];
#pragma unroll
                for (int mt = 0; mt < 4; ++mt)
                    af[mt] = *(const bf16x8*)(hbuf + c * 2048 + aoff + mt * 512);
#pragma unroll
                for (int mt = 0; mt < 4; ++mt) {
                    acc[mt][0] = MFMA(af[mt], w2c[c][0], acc[mt][0]);
                    acc[mt][1] = MFMA(af[mt], w2c[c][1], acc[mt][1]);
                    acc[mt][3] = MFMA(af[mt], w2c[c][2], acc[mt][3]);
                }
            }
        }
        // s == 0: h = 0, so gh = bhh exactly — already folded into b_r/b_z/b_nh.

        // ---- epilogue: GRU cell, reg-resident h & masked sum, publish bf16 h ----
        {
            __bf16* hb_w = HB[(s & 1) ^ 1];
            const bool store_lane = (lane & 1) == 0;
#pragma unroll
            for (int mt = 0; mt < 4; ++mt) {
#pragma unroll
                for (int reg = 0; reg < 4; ++reg) {
                    const int i = mt * 4 + reg;
                    const float r = 1.f / (1.f + __expf(-(acc[mt][0][reg] + b_r)));
                    const float z = 1.f / (1.f + __expf(-(acc[mt][1][reg] + b_z)));
                    const float nv = acc[mt][2][reg] + b_ni + r * (acc[mt][3][reg] + b_nh);
                    const float n = 2.f / (1.f + __expf(-2.f * nv)) - 1.f;   // tanh
                    const float hnew = (1.f - z) * n + z * hreg[i];
                    hreg[i] = hnew;
                    if (((lenp[mt] >> (reg * 8)) & 255u) > (unsigned)s) ssum[i] += hnew;
                    __bf16 hb16 = (__bf16)hnew;
                    unsigned short myb = __builtin_bit_cast(unsigned short, hb16);
                    unsigned ob = (unsigned)__shfl_xor((int)(unsigned)myb, 1, 64);
                    if (store_lane) {
                        const int b = b0 + mt * 16 + (lane >> 4) * 4 + reg;
                        unsigned packed = (unsigned)myb | (ob << 16);
                        __hip_atomic_store(
                            (unsigned*)(hb_w + (size_t)(dir * B_ + b) * H_ + jcol),
                            packed, __ATOMIC_RELAXED, __HIP_MEMORY_SCOPE_AGENT);
                    }
                }
            }
        }
        __syncthreads();   // compiler drains vmcnt before s_barrier => stores at L3
        if (tid == 0 && s < S_ - 1)
            __hip_atomic_fetch_add(gcnt, 1u, __ATOMIC_RELAXED,
                                   __HIP_MEMORY_SCOPE_AGENT);
    }

    // write masked sums (consumed by next kernel; dispatch-boundary flush)
#pragma unroll
    for (int mt = 0; mt < 4; ++mt)
#pragma unroll
        for (int reg = 0; reg < 4; ++reg) {
            const int b = b0 + mt * 16 + (lane >> 4) * 4 + reg;
            Ssum[(size_t)(dir * B_ + b) * H_ + jcol] = ssum[mt * 4 + reg];
        }
}

// ---------------- head ----------------
__global__ __launch_bounds__(128) void avg_prep(const float* __restrict__ Ssum,
                                                const int* __restrict__ lens,
                                                __bf16* __restrict__ Avg) {
    int b = blockIdx.x, t = threadIdx.x;
    float inv = 0.5f / (float)lens[b];
    float4 a = *(const float4*)(Ssum + (size_t)b * H_ + t * 4);
    float4 c = *(const float4*)(Ssum + (size_t)(B_ + b) * H_ + t * 4);
    __bf16* dst = Avg + (size_t)b * H_ + t * 4;
    dst[0] = (__bf16)((a.x + c.x) * inv);
    dst[1] = (__bf16)((a.y + c.y) * inv);
    dst[2] = (__bf16)((a.z + c.z) * inv);
    dst[3] = (__bf16)((a.w + c.w) * inv);
}

// Avg[1024x512] @ Wcat[256x512]^T -> mu/sigma planes of out
__global__ __launch_bounds__(256) void head_gemm(
    const __bf16* __restrict__ Avg, const __bf16* __restrict__ Wcat,
    const float* __restrict__ b_mu, const float* __restrict__ b_sig,
    float* __restrict__ out)
{
    __shared__ __align__(16) __bf16 abuf[16 * 2048];   // 64 KB static
    const int bid = blockIdx.x;                        // 64
    const int mb = bid >> 2, jb = bid & 3;
    const int tid = threadIdx.x, wave = tid >> 6, lane = tid & 63;
    const int srow = tid >> 2, scol = (tid & 3) * 8;
    const __bf16* asrc = Avg + (size_t)(mb * 64 + srow) * H_ + scol;
    {
        __bf16* dst = abuf + wave * 512;
#pragma unroll
        for (int c = 0; c < 16; ++c) GLLD(asrc + c * 32, dst + c * 2048);
    }
    __syncthreads();
    const int j = jb * 64 + wave * 16 + (lane & 15);   // 0..255
    const int kq8 = (lane >> 4) * 8;
    const __bf16* wp = Wcat + (size_t)j * H_ + kq8;
    const int aoff = (lane & 15) * 32 + kq8;
    f32x4 acc[4];
#pragma unroll
    for (int mt = 0; mt < 4; ++mt) acc[mt] = (f32x4){0.f, 0.f, 0.f, 0.f};
#pragma unroll
    for (int c = 0; c < 16; ++c) {
        bf16x8 wf = *(const bf16x8*)(wp + c * 32);
#pragma unroll
        for (int mt = 0; mt < 4; ++mt) {
            bf16x8 af = *(const bf16x8*)(abuf + c * 2048 + aoff + mt * 512);
            acc[mt] = MFMA(af, wf, acc[mt]);
        }
    }
    const int gate = j >> 7, z = j & 127;
    const float bias = gate ? b_sig[z] : b_mu[z];
#pragma unroll
    for (int mt = 0; mt < 4; ++mt)
#pragma unroll
        for (int reg = 0; reg < 4; ++reg) {
            const int b = mb * 64 + mt * 16 + (lane >> 4) * 4 + reg;
            float v = acc[mt][reg] + bias;
            v = v >= 0.f ? v : 0.2f * v;
            if (gate) v = __expf(v);
            out[(size_t)(1 + gate) * B_ * Z_ + (size_t)b * Z_ + z] = v;
        }
}

__global__ __launch_bounds__(256) void final_k(const float* __restrict__ eps,
                                               float* __restrict__ out) {
    int i = blockIdx.x * 256 + threadIdx.x;    // 131072
    out[i] = eps[i] * out[2 * B_ * Z_ + i] + out[B_ * Z_ + i];
}

extern "C" void kernel_launch(void* const* d_in, const int* in_sizes, int n_in,
                              void* d_out, int out_size, void* d_ws, size_t ws_size,
                              hipStream_t stream) {
    const float* text  = (const float*)d_in[0];
    const int*   lens  = (const int*)  d_in[1];
    const float* Wih_f = (const float*)d_in[2];
    const float* Whh_f = (const float*)d_in[3];
    const float* bih_f = (const float*)d_in[4];
    const float* bhh_f = (const float*)d_in[5];
    const float* Wih_b = (const float*)d_in[6];
    const float* Whh_b = (const float*)d_in[7];
    const float* bih_b = (const float*)d_in[8];
    const float* bhh_b = (const float*)d_in[9];
    const float* W_mu  = (const float*)d_in[10];
    const float* b_mu  = (const float*)d_in[11];
    const float* W_sig = (const float*)d_in[12];
    const float* b_sig = (const float*)d_in[13];
    const float* eps   = (const float*)d_in[14];
    float* out = (float*)d_out;

    char* ws = (char*)d_ws;
    __bf16* Xbf  = (__bf16*)(ws);                   // 41943040
    __bf16* Wk1  = (__bf16*)(ws + 41943040);        //  1966080
    __bf16* Wk2  = (__bf16*)(ws + 43909120);        //  3145728
    __bf16* Hb0  = (__bf16*)(ws + 47054848);        //  2097152
    __bf16* Hb1  = (__bf16*)(ws + 49152000);        //  2097152
    float*  Ssum = (float*) (ws + 51249152);        //  4194304
    __bf16* Avg  = (__bf16*)(ws + 55443456);        //  1048576
    __bf16* Wcat = (__bf16*)(ws + 56492032);        //   262144
    unsigned* cntp = (unsigned*)(ws + 56754176);    //     8192 (32 groups x 256 B)
    // total 56762368 bytes

    prep_cnt<<<8, 256, 0, stream>>>(cntp);
    prep_text<<<B_ * S_, 320, 0, stream>>>(text, Xbf);
    prep_w<<<10496, 256, 0, stream>>>(Wih_f, Whh_f, Wih_b, Whh_b, W_mu, W_sig,
                                      Wk1, Wk2, Wcat);

    void* args[] = { (void*)&Xbf, (void*)&Wk1, (void*)&Wk2,
                     (void*)&bih_f, (void*)&bhh_f, (void*)&bih_b, (void*)&bhh_b,
                     (void*)&lens, (void*)&Hb0, (void*)&Hb1,
                     (void*)&Ssum, (void*)&cntp };
    hipError_t ce = hipLaunchCooperativeKernel((void*)gru_persist, dim3(256),
                                               dim3(256), args, 0, stream);
    if (ce != hipSuccess) {
        gru_persist<<<256, 256, 0, stream>>>(Xbf, Wk1, Wk2,
                                             bih_f, bhh_f, bih_b, bhh_b,
                                             lens, Hb0, Hb1, Ssum, cntp);
    }

    avg_prep<<<B_, 128, 0, stream>>>(Ssum, lens, Avg);
    head_gemm<<<64, 256, 0, stream>>>(Avg, Wcat, b_mu, b_sig, out);
    final_k<<<512, 256, 0, stream>>>(eps, out);
}

// Round 8
// 1312.066 us; speedup vs baseline: 1.1243x; 1.1243x over previous
//
#include <hip/hip_runtime.h>

#define B_ 1024
#define S_ 64
#define D_ 300
#define DP_ 320
#define H_ 512
#define G3_ 1536
#define Z_ 128
#define NC1 10
#define NC2 16
#define CSTR 64   // counter stride in dwords (256 B line per group)

typedef __bf16 bf16x8 __attribute__((ext_vector_type(8)));
typedef float f32x4 __attribute__((ext_vector_type(4)));

// cached global->LDS DMA (aux=0)
#define GLLD(g, l) __builtin_amdgcn_global_load_lds( \
    (const __attribute__((address_space(1))) void*)(g), \
    (__attribute__((address_space(3))) void*)(l), 16, 0, 0)
// L2-coherent global->LDS DMA: aux=1 = SC0 -> bypass L1, served by (same-XCD) L2
#define GLLD_L2(g, l) __builtin_amdgcn_global_load_lds( \
    (const __attribute__((address_space(1))) void*)(g), \
    (__attribute__((address_space(3))) void*)(l), 16, 0, 1)

#define MFMA(a, b, c) __builtin_amdgcn_mfma_f32_16x16x32_bf16((a), (b), (c), 0, 0, 0)

// ---------------- prep kernels ----------------
__global__ __launch_bounds__(256) void prep_cnt(unsigned* __restrict__ cnt) {
    int i = blockIdx.x * 256 + threadIdx.x;        // 2048 dwords
    cnt[i] = 0u;
}

// text is [b][s][d]; Xbf re-laid-out to [s][b][dp] so each step's tile is contiguous
__global__ __launch_bounds__(320) void prep_text(const float* __restrict__ text,
                                                 __bf16* __restrict__ Xbf) {
    int bs = blockIdx.x;          // 65536 = B*S, bs = b*S + s
    int b = bs >> 6, s = bs & 63;
    int dp = threadIdx.x;         // 320
    float v = (dp < D_) ? text[(size_t)bs * D_ + dp] : 0.f;
    Xbf[((size_t)s * B_ + b) * DP_ + dp] = (__bf16)v;
}

__global__ __launch_bounds__(256) void prep_w(
    const float* __restrict__ Wih_f, const float* __restrict__ Whh_f,
    const float* __restrict__ Wih_b, const float* __restrict__ Whh_b,
    const float* __restrict__ W_mu, const float* __restrict__ W_sig,
    __bf16* __restrict__ Wk1, __bf16* __restrict__ Wk2, __bf16* __restrict__ Wcat) {
    const int n1 = 2 * G3_ * DP_;       // 983040
    const int n2 = 2 * G3_ * H_;        // 1572864
    int i = blockIdx.x * 256 + threadIdx.x;
    if (i < n1) {
        int dir = i / (G3_ * DP_);
        int rem = i - dir * (G3_ * DP_);
        int r = rem / DP_;
        int k = rem - r * DP_;
        const float* W = dir ? Wih_b : Wih_f;
        Wk1[i] = (k < D_) ? (__bf16)W[(size_t)r * D_ + k] : (__bf16)0.f;
    } else if (i < n1 + n2) {
        int jj = i - n1;
        int dir = jj / (G3_ * H_);
        int rem = jj - dir * (G3_ * H_);
        int r = rem / H_;
        int k = rem - r * H_;
        const float* W = dir ? Whh_b : Whh_f;
        Wk2[jj] = (__bf16)W[(size_t)r * H_ + k];
    } else {
        int idx = i - n1 - n2;          // < 131072
        int z = idx >> 9, k = idx & 511;
        Wcat[idx] = (__bf16)(z < 128 ? W_mu[(size_t)z * H_ + k]
                                     : W_sig[(size_t)(z - 128) * H_ + k]);
    }
}

// ---------------- persistent bidirectional GRU ----------------
// 256 blocks, 256 threads (4 waves). Block = 64 batch rows x 64 h-cols of one
// direction. Weights register/AGPR-resident across all 64 steps; h and the
// masked sum register-resident.
// KEY CHANGE (r8): each sync group's 8 blocks share bid&7, and MI355X places
// blocks round-robin over XCDs (XCD = blockIdx % 8) -> the whole group shares
// ONE per-XCD L2. So the cross-block h exchange runs entirely at the L2 point:
//   - h published with plain cached stores (CDNA L1 is write-through -> L2)
//   - h read via global_load_lds aux=SC0 (L1 bypass, L2-served)
//   - step-barrier counters are workgroup-scope atomic RMWs (no sc1 -> they
//     execute at the same-XCD L2); polling uses fetch_add(0) so the read is
//     also an L2-point RMW (never L1-stale).
// Bounded spin turns a wrong-placement deadlock into a wrong answer, not a hang.
// s=0 skips the exchange (h0 = 0, bhh folded into biases).
__global__ __launch_bounds__(256, 1) void gru_persist(
    const __bf16* __restrict__ Xbf, const __bf16* __restrict__ Wk1,
    const __bf16* __restrict__ Wk2,
    const float* __restrict__ bih_f, const float* __restrict__ bhh_f,
    const float* __restrict__ bih_b, const float* __restrict__ bhh_b,
    const int* __restrict__ lens,
    __bf16* __restrict__ Hb0, __bf16* __restrict__ Hb1,
    float* __restrict__ Ssum, unsigned* __restrict__ cnt)
{
    __shared__ __align__(16) __bf16 hbuf[NC2 * 2048];   // 64 KB static

    const int bid = blockIdx.x;
    const int xcd = bid & 7, slot = bid >> 3;
    const int dir = xcd >> 2;
    const int mb  = (xcd & 3) * 4 + (slot >> 3);   // 0..15
    const int jb  = slot & 7;                      // 0..7
    const int b0  = mb * 64;
    const int group = dir * 16 + mb;               // all 8 members share bid&7
    unsigned* const gcnt = cnt + group * CSTR;

    const int tid = threadIdx.x;
    const int wave = tid >> 6;
    const int lane = tid & 63;

    const int jcol = jb * 64 + wave * 16 + (lane & 15);    // 0..511
    const int kq8  = (lane >> 4) * 8;

    __bf16* HB[2] = { Hb0, Hb1 };
    // h staging geometry (thread -> row, col-quad), matches chunk layout [64][32]
    const int srow = tid >> 2;
    const int scol = (tid & 3) * 8;
    const size_t hrow = (size_t)(dir * B_ + b0 + srow) * H_ + scol;

    // per-lane X base: row b0+(lane&15), col kq8 (chunk c adds c*32, mt adds 16*DP_)
    const __bf16* xlane = Xbf + (size_t)(b0 + (lane & 15)) * DP_ + kq8;

    // ---- one-time: load BOTH weight slices into registers ----
    bf16x8 w1c[NC1][3];   // Wih fragments
    bf16x8 w2c[NC2][3];   // Whh fragments
    {
        const __bf16* w1p[3];
        const __bf16* w2p[3];
#pragma unroll
        for (int g = 0; g < 3; ++g) {
            w1p[g] = Wk1 + ((size_t)dir * G3_ + g * H_ + jcol) * DP_ + kq8;
            w2p[g] = Wk2 + ((size_t)dir * G3_ + g * H_ + jcol) * H_ + kq8;
        }
#pragma unroll
        for (int c = 0; c < NC1; ++c)
#pragma unroll
            for (int g = 0; g < 3; ++g)
                w1c[c][g] = *(const bf16x8*)(w1p[g] + c * 32);
#pragma unroll
        for (int c = 0; c < NC2; ++c)
#pragma unroll
            for (int g = 0; g < 3; ++g)
                w2c[c][g] = *(const bf16x8*)(w2p[g] + c * 32);
    }

    const float* bih = dir ? bih_b : bih_f;
    const float* bhh = dir ? bhh_b : bhh_f;
    const float b_r  = bih[jcol] + bhh[jcol];
    const float b_z  = bih[H_ + jcol] + bhh[H_ + jcol];
    const float b_ni = bih[2 * H_ + jcol];
    const float b_nh = bhh[2 * H_ + jcol];

    unsigned lenp[4];
#pragma unroll
    for (int mt = 0; mt < 4; ++mt) {
        int r0 = b0 + mt * 16 + (lane >> 4) * 4;
        lenp[mt] = (unsigned)(lens[r0] & 255) | ((unsigned)(lens[r0 + 1] & 255) << 8)
                 | ((unsigned)(lens[r0 + 2] & 255) << 16) | ((unsigned)(lens[r0 + 3] & 255) << 24);
    }

    float hreg[16], ssum[16];
#pragma unroll
    for (int i = 0; i < 16; ++i) { hreg[i] = 0.f; ssum[i] = 0.f; }

    const int aoff = (lane & 15) * 32 + kq8;

    for (int s = 0; s < S_; ++s) {
        const int sx = dir ? (S_ - 1 - s) : s;
        const __bf16* xs = xlane + (size_t)sx * (B_ * DP_);

        f32x4 acc[4][4];
#pragma unroll
        for (int mt = 0; mt < 4; ++mt)
#pragma unroll
            for (int p = 0; p < 4; ++p)
                acc[mt][p] = (f32x4){0.f, 0.f, 0.f, 0.f};

        // ---- phase 1: x @ Wih^T (W in registers, X from L2; overlaps peers' tail) ----
#pragma unroll
        for (int c = 0; c < NC1; ++c) {
            bf16x8 af[4];
#pragma unroll
            for (int mt = 0; mt < 4; ++mt)
                af[mt] = *(const bf16x8*)(xs + mt * (16 * DP_) + c * 32);
#pragma unroll
            for (int mt = 0; mt < 4; ++mt) {
                acc[mt][0] = MFMA(af[mt], w1c[c][0], acc[mt][0]);
                acc[mt][1] = MFMA(af[mt], w1c[c][1], acc[mt][1]);
                acc[mt][2] = MFMA(af[mt], w1c[c][2], acc[mt][2]);
            }
        }

        if (s > 0) {
            // ---- wait for group peers (L2-point RMW poll; bounded spin) ----
            if (tid == 0) {
                const unsigned tgt = 8u * (unsigned)s;
                unsigned it = 0;
                while (__hip_atomic_fetch_add(gcnt, 0u, __ATOMIC_RELAXED,
                                              __HIP_MEMORY_SCOPE_WORKGROUP) < tgt) {
                    if (++it > (1u << 20)) break;   // placement-failure escape
                }
            }
            __syncthreads();

            // ---- stage h via pipelined L2-coherent global->LDS DMA ----
            {
                const __bf16* src = HB[s & 1] + hrow;     // per-lane source
                __bf16* dst = hbuf + wave * 512;          // wave-uniform + lane*16B
#pragma unroll
                for (int c = 0; c < NC2; ++c)
                    GLLD_L2(src + c * 32, dst + c * 2048);
            }
            __syncthreads();   // vmcnt(0) drains the DMA

            // ---- phase 2: h @ Whh^T (W in registers) ----
#pragma unroll
            for (int c = 0; c < NC2; ++c) {
                bf16x8 af[4];
#pragma unroll
                for (int mt = 0; mt < 4; ++mt)
                    af[mt] = *(const bf16x8*)(hbuf + c * 2048 + aoff + mt * 512);
#pragma unroll
                for (int mt = 0; mt < 4; ++mt) {
                    acc[mt][0] = MFMA(af[mt], w2c[c][0], acc[mt][0]);
                    acc[mt][1] = MFMA(af[mt], w2c[c][1], acc[mt][1]);
                    acc[mt][3] = MFMA(af[mt], w2c[c][2], acc[mt][3]);
                }
            }
        }
        // s == 0: h = 0, so gh = bhh exactly — already folded into b_r/b_z/b_nh.

        // ---- epilogue: GRU cell, reg-resident h & masked sum, publish bf16 h ----
        {
            __bf16* hb_w = HB[(s & 1) ^ 1];
            const bool store_lane = (lane & 1) == 0;
#pragma unroll
            for (int mt = 0; mt < 4; ++mt) {
#pragma unroll
                for (int reg = 0; reg < 4; ++reg) {
                    const int i = mt * 4 + reg;
                    const float r = 1.f / (1.f + __expf(-(acc[mt][0][reg] + b_r)));
                    const float z = 1.f / (1.f + __expf(-(acc[mt][1][reg] + b_z)));
                    const float nv = acc[mt][2][reg] + b_ni + r * (acc[mt][3][reg] + b_nh);
                    const float n = 2.f / (1.f + __expf(-2.f * nv)) - 1.f;   // tanh
                    const float hnew = (1.f - z) * n + z * hreg[i];
                    hreg[i] = hnew;
                    if (((lenp[mt] >> (reg * 8)) & 255u) > (unsigned)s) ssum[i] += hnew;
                    __bf16 hb16 = (__bf16)hnew;
                    unsigned short myb = __builtin_bit_cast(unsigned short, hb16);
                    unsigned ob = (unsigned)__shfl_xor((int)(unsigned)myb, 1, 64);
                    if (store_lane) {
                        const int b = b0 + mt * 16 + (lane >> 4) * 4 + reg;
                        // plain cached store: write-through L1 -> lands in same-XCD L2
                        *(unsigned*)(hb_w + (size_t)(dir * B_ + b) * H_ + jcol) =
                            (unsigned)myb | (ob << 16);
                    }
                }
            }
        }
        __syncthreads();   // drains vmcnt => h stores acknowledged by L2
        if (tid == 0 && s < S_ - 1)
            __hip_atomic_fetch_add(gcnt, 1u, __ATOMIC_RELAXED,
                                   __HIP_MEMORY_SCOPE_WORKGROUP);   // L2-point
    }

    // write masked sums (consumed by next kernel; dispatch-boundary flush)
#pragma unroll
    for (int mt = 0; mt < 4; ++mt)
#pragma unroll
        for (int reg = 0; reg < 4; ++reg) {
            const int b = b0 + mt * 16 + (lane >> 4) * 4 + reg;
            Ssum[(size_t)(dir * B_ + b) * H_ + jcol] = ssum[mt * 4 + reg];
        }
}

// ---------------- head ----------------
__global__ __launch_bounds__(128) void avg_prep(const float* __restrict__ Ssum,
                                                const int* __restrict__ lens,
                                                __bf16* __restrict__ Avg) {
    int b = blockIdx.x, t = threadIdx.x;
    float inv = 0.5f / (float)lens[b];
    float4 a = *(const float4*)(Ssum + (size_t)b * H_ + t * 4);
    float4 c = *(const float4*)(Ssum + (size_t)(B_ + b) * H_ + t * 4);
    __bf16* dst = Avg + (size_t)b * H_ + t * 4;
    dst[0] = (__bf16)((a.x + c.x) * inv);
    dst[1] = (__bf16)((a.y + c.y) * inv);
    dst[2] = (__bf16)((a.z + c.z) * inv);
    dst[3] = (__bf16)((a.w + c.w) * inv);
}

// Avg[1024x512] @ Wcat[256x512]^T -> mu/sigma planes of out
__global__ __launch_bounds__(256) void head_gemm(
    const __bf16* __restrict__ Avg, const __bf16* __restrict__ Wcat,
    const float* __restrict__ b_mu, const float* __restrict__ b_sig,
    float* __restrict__ out)
{
    __shared__ __align__(16) __bf16 abuf[16 * 2048];   // 64 KB static
    const int bid = blockIdx.x;                        // 64
    const int mb = bid >> 2, jb = bid & 3;
    const int tid = threadIdx.x, wave = tid >> 6, lane = tid & 63;
    const int srow = tid >> 2, scol = (tid & 3) * 8;
    const __bf16* asrc = Avg + (size_t)(mb * 64 + srow) * H_ + scol;
    {
        __bf16* dst = abuf + wave * 512;
#pragma unroll
        for (int c = 0; c < 16; ++c) GLLD(asrc + c * 32, dst + c * 2048);
    }
    __syncthreads();
    const int j = jb * 64 + wave * 16 + (lane & 15);   // 0..255
    const int kq8 = (lane >> 4) * 8;
    const __bf16* wp = Wcat + (size_t)j * H_ + kq8;
    const int aoff = (lane & 15) * 32 + kq8;
    f32x4 acc[4];
#pragma unroll
    for (int mt = 0; mt < 4; ++mt) acc[mt] = (f32x4){0.f, 0.f, 0.f, 0.f};
#pragma unroll
    for (int c = 0; c < 16; ++c) {
        bf16x8 wf = *(const bf16x8*)(wp + c * 32);
#pragma unroll
        for (int mt = 0; mt < 4; ++mt) {
            bf16x8 af = *(const bf16x8*)(abuf + c * 2048 + aoff + mt * 512);
            acc[mt] = MFMA(af, wf, acc[mt]);
        }
    }
    const int gate = j >> 7, z = j & 127;
    const float bias = gate ? b_sig[z] : b_mu[z];
#pragma unroll
    for (int mt = 0; mt < 4; ++mt)
#pragma unroll
        for (int reg = 0; reg < 4; ++reg) {
            const int b = mb * 64 + mt * 16 + (lane >> 4) * 4 + reg;
            float v = acc[mt][reg] + bias;
            v = v >= 0.f ? v : 0.2f * v;
            if (gate) v = __expf(v);
            out[(size_t)(1 + gate) * B_ * Z_ + (size_t)b * Z_ + z] = v;
        }
}

__global__ __launch_bounds__(256) void final_k(const float* __restrict__ eps,
                                               float* __restrict__ out) {
    int i = blockIdx.x * 256 + threadIdx.x;    // 131072
    out[i] = eps[i] * out[2 * B_ * Z_ + i] + out[B_ * Z_ + i];
}

extern "C" void kernel_launch(void* const* d_in, const int* in_sizes, int n_in,
                              void* d_out, int out_size, void* d_ws, size_t ws_size,
                              hipStream_t stream) {
    const float* text  = (const float*)d_in[0];
    const int*   lens  = (const int*)  d_in[1];
    const float* Wih_f = (const float*)d_in[2];
    const float* Whh_f = (const float*)d_in[3];
    const float* bih_f = (const float*)d_in[4];
    const float* bhh_f = (const float*)d_in[5];
    const float* Wih_b = (const float*)d_in[6];
    const float* Whh_b = (const float*)d_in[7];
    const float* bih_b = (const float*)d_in[8];
    const float* bhh_b = (const float*)d_in[9];
    const float* W_mu  = (const float*)d_in[10];
    const float* b_mu  = (const float*)d_in[11];
    const float* W_sig = (const float*)d_in[12];
    const float* b_sig = (const float*)d_in[13];
    const float* eps   = (const float*)d_in[14];
    float* out = (float*)d_out;

    char* ws = (char*)d_ws;
    __bf16* Xbf  = (__bf16*)(ws);                   // 41943040
    __bf16* Wk1  = (__bf16*)(ws + 41943040);        //  1966080
    __bf16* Wk2  = (__bf16*)(ws + 43909120);        //  3145728
    __bf16* Hb0  = (__bf16*)(ws + 47054848);        //  2097152
    __bf16* Hb1  = (__bf16*)(ws + 49152000);        //  2097152
    float*  Ssum = (float*) (ws + 51249152);        //  4194304
    __bf16* Avg  = (__bf16*)(ws + 55443456);        //  1048576
    __bf16* Wcat = (__bf16*)(ws + 56492032);        //   262144
    unsigned* cntp = (unsigned*)(ws + 56754176);    //     8192 (32 groups x 256 B)
    // total 56762368 bytes

    prep_cnt<<<8, 256, 0, stream>>>(cntp);
    prep_text<<<B_ * S_, 320, 0, stream>>>(text, Xbf);
    prep_w<<<10496, 256, 0, stream>>>(Wih_f, Whh_f, Wih_b, Whh_b, W_mu, W_sig,
                                      Wk1, Wk2, Wcat);

    void* args[] = { (void*)&Xbf, (void*)&Wk1, (void*)&Wk2,
                     (void*)&bih_f, (void*)&bhh_f, (void*)&bih_b, (void*)&bhh_b,
                     (void*)&lens, (void*)&Hb0, (void*)&Hb1,
                     (void*)&Ssum, (void*)&cntp };
    hipError_t ce = hipLaunchCooperativeKernel((void*)gru_persist, dim3(256),
                                               dim3(256), args, 0, stream);
    if (ce != hipSuccess) {
        gru_persist<<<256, 256, 0, stream>>>(Xbf, Wk1, Wk2,
                                             bih_f, bhh_f, bih_b, bhh_b,
                                             lens, Hb0, Hb1, Ssum, cntp);
    }

    avg_prep<<<B_, 128, 0, stream>>>(Ssum, lens, Avg);
    head_gemm<<<64, 256, 0, stream>>>(Avg, Wcat, b_mu, b_sig, out);
    final_k<<<512, 256, 0, stream>>>(eps, out);
}